// Round 3
// baseline (2108.610 us; speedup 1.0000x reference)
//
#include <hip/hip_runtime.h>
#include <cstdint>

#define NN 50000
#define DD 128
#define EE 600000

__device__ __forceinline__ float sigmoid_f(float x) {
    return 1.0f / (1.0f + __expf(-x));
}
__device__ __forceinline__ float tanh_f(float x) {
    float e = __expf(-2.0f * fabsf(x));
    float t = (1.0f - e) / (1.0f + e);
    return copysignf(t, x);
}

// ---- weight packing -----------------------------------------------------
// wpk[((k*6 + g)*128) + c], c = jblk*4 + j' (c in [0,128))
//   g=0..2: wx gates r,i,n : wx[(g*128 + c)*128 + k]
//   g=3..5: wh gates r,i,n : wh[((g-3)*128 + c)*128 + k]
// Per (k,g) a wave's 32 tj-lanes read wpk + (k*6+g)*128 + tj*4 -> one
// contiguous 512B segment (perfect coalescing).
__global__ __launch_bounds__(256) void pack_w_kernel(const float* __restrict__ wx,
                                                     const float* __restrict__ wh,
                                                     float* __restrict__ wpk) {
    int idx = blockIdx.x * 256 + threadIdx.x;
    if (idx >= 128 * 6 * 128) return;
    int k = idx / 768;
    int r1 = idx - k * 768;
    int g = r1 >> 7;
    int c = r1 & 127;
    float v = (g < 3) ? wx[(g * 128 + c) * 128 + k]
                      : wh[((g - 3) * 128 + c) * 128 + k];
    wpk[idx] = v;
}

// ---- CSR build ----------------------------------------------------------

__global__ __launch_bounds__(256) void hist_kernel(const int* __restrict__ rows,
                                                   int* __restrict__ cnt) {
    int e = blockIdx.x * 256 + threadIdx.x;
    if (e >= EE) return;
    atomicAdd(&cnt[rows[e]], 1);
}

// exclusive scan of cnt[0..NN) -> row_ptr[0..NN]; single block of 1024
__global__ __launch_bounds__(1024) void scan_kernel(const int* __restrict__ cnt,
                                                    int* __restrict__ row_ptr) {
    __shared__ int buf[1024];
    const int tid = threadIdx.x;
    const int CH = (NN + 1023) / 1024;  // 49
    const int base = tid * CH;
    int s = 0;
    #pragma unroll
    for (int i = 0; i < CH; ++i) {
        int idx = base + i;
        if (idx < NN) s += cnt[idx];
    }
    buf[tid] = s;
    __syncthreads();
    for (int d = 1; d < 1024; d <<= 1) {
        int t = (tid >= d) ? buf[tid - d] : 0;
        __syncthreads();
        buf[tid] += t;
        __syncthreads();
    }
    int run = buf[tid] - s;
    #pragma unroll
    for (int i = 0; i < CH; ++i) {
        int idx = base + i;
        if (idx < NN) {
            row_ptr[idx] = run;
            run += cnt[idx];
        }
    }
    if (tid == 0) row_ptr[NN] = EE;
}

__global__ __launch_bounds__(256) void scatter_kernel(const int* __restrict__ rows,
                                                      const int* __restrict__ cols,
                                                      const float* __restrict__ vals,
                                                      int* __restrict__ cursor,
                                                      int* __restrict__ ecol,
                                                      float* __restrict__ eval) {
    int e = blockIdx.x * 256 + threadIdx.x;
    if (e >= EE) return;
    int r = rows[e];
    int pos = atomicAdd(&cursor[r], 1);
    ecol[pos] = cols[e];
    eval[pos] = vals[e];
}

// ---- SpMM as CSR gather: res[r] = relu(sum_e val*x[col]) ---------------
// one wave64 per row, float2 per lane, 4-edge ILP
__global__ __launch_bounds__(256) void gather_kernel(const float* __restrict__ x,
                                                     const int* __restrict__ row_ptr,
                                                     const int* __restrict__ ecol,
                                                     const float* __restrict__ eval,
                                                     float* __restrict__ res) {
    const int tid = threadIdx.x;
    const int lane = tid & 63;
    const int row = blockIdx.x * 4 + (tid >> 6);
    if (row >= NN) return;
    const int start = row_ptr[row];
    const int end = row_ptr[row + 1];
    const int d0 = lane * 2;
    float a0x = 0.f, a0y = 0.f, a1x = 0.f, a1y = 0.f;
    float a2x = 0.f, a2y = 0.f, a3x = 0.f, a3y = 0.f;
    int e = start;
    for (; e + 3 < end; e += 4) {
        int c0 = ecol[e], c1 = ecol[e + 1], c2 = ecol[e + 2], c3 = ecol[e + 3];
        float v0 = eval[e], v1 = eval[e + 1], v2 = eval[e + 2], v3 = eval[e + 3];
        float2 p0 = *reinterpret_cast<const float2*>(x + (size_t)c0 * DD + d0);
        float2 p1 = *reinterpret_cast<const float2*>(x + (size_t)c1 * DD + d0);
        float2 p2 = *reinterpret_cast<const float2*>(x + (size_t)c2 * DD + d0);
        float2 p3 = *reinterpret_cast<const float2*>(x + (size_t)c3 * DD + d0);
        a0x += v0 * p0.x; a0y += v0 * p0.y;
        a1x += v1 * p1.x; a1y += v1 * p1.y;
        a2x += v2 * p2.x; a2y += v2 * p2.y;
        a3x += v3 * p3.x; a3y += v3 * p3.y;
    }
    for (; e < end; ++e) {
        int c0 = ecol[e];
        float v0 = eval[e];
        float2 p0 = *reinterpret_cast<const float2*>(x + (size_t)c0 * DD + d0);
        a0x += v0 * p0.x; a0y += v0 * p0.y;
    }
    float2 o;
    o.x = fmaxf((a0x + a1x) + (a2x + a3x), 0.f);
    o.y = fmaxf((a0y + a1y) + (a2y + a3y), 0.f);
    *reinterpret_cast<float2*>(res + (size_t)row * DD + d0) = o;
}

// ---- Fused dual-GEMM + GRU (+LN on last step) ---------------------------
// Block: 32 rows x all 128 out-cols, 256 threads, thread = 4 rows x 4 cols.
// Weights read directly from packed global (L1/L2-resident, coalesced 512B
// segments); inputs from LDS with full-broadcast b128 reads. ONE barrier.
template <bool FIRST, bool LAST>
__global__ __launch_bounds__(256) void gru_step_kernel(const float* __restrict__ res,
                                                       float* __restrict__ h,
                                                       const float* __restrict__ wpk,
                                                       const float* __restrict__ bx,
                                                       const float* __restrict__ bh,
                                                       const float* __restrict__ lng,
                                                       const float* __restrict__ lnb) {
    __shared__ float s_res[32 * DD];   // 16 KB
    __shared__ float s_h[32 * DD];     // 16 KB

    const int tid = threadIdx.x;
    const int row0 = blockIdx.x * 32;

    #pragma unroll
    for (int p = 0; p < 4; ++p) {
        int i = tid + p * 256;
        int rl = i >> 5;
        int f4 = (i & 31) * 4;
        int row = row0 + rl;
        float4 rv = make_float4(0.f, 0.f, 0.f, 0.f);
        float4 hv = make_float4(0.f, 0.f, 0.f, 0.f);
        if (row < NN) {
            rv = *reinterpret_cast<const float4*>(res + (size_t)row * DD + f4);
            if (!FIRST) hv = *reinterpret_cast<const float4*>(h + (size_t)row * DD + f4);
        }
        *reinterpret_cast<float4*>(&s_res[rl * DD + f4]) = rv;
        if (!FIRST) *reinterpret_cast<float4*>(&s_h[rl * DD + f4]) = hv;
    }

    const int tj = tid & 31;
    const int rt = tid >> 5;   // 0..7
    const int jb = tj * 4;

    float sr[4][4], si[4][4], sn[4][4], hn[4][4];
    {
        float4 bxr = *reinterpret_cast<const float4*>(bx + jb);
        float4 bxi = *reinterpret_cast<const float4*>(bx + DD + jb);
        float4 bxn = *reinterpret_cast<const float4*>(bx + 2 * DD + jb);
        float4 bhr = *reinterpret_cast<const float4*>(bh + jb);
        float4 bhi = *reinterpret_cast<const float4*>(bh + DD + jb);
        float4 bhn = *reinterpret_cast<const float4*>(bh + 2 * DD + jb);
        #pragma unroll
        for (int r = 0; r < 4; ++r) {
            sr[r][0] = bxr.x + bhr.x; sr[r][1] = bxr.y + bhr.y;
            sr[r][2] = bxr.z + bhr.z; sr[r][3] = bxr.w + bhr.w;
            si[r][0] = bxi.x + bhi.x; si[r][1] = bxi.y + bhi.y;
            si[r][2] = bxi.z + bhi.z; si[r][3] = bxi.w + bhi.w;
            sn[r][0] = bxn.x; sn[r][1] = bxn.y; sn[r][2] = bxn.z; sn[r][3] = bxn.w;
            hn[r][0] = bhn.x; hn[r][1] = bhn.y; hn[r][2] = bhn.z; hn[r][3] = bhn.w;
        }
    }

    __syncthreads();   // the ONLY barrier

    const float* wb = wpk + (tj << 2);

    #pragma unroll 2
    for (int k0 = 0; k0 < DD; k0 += 4) {
        float av[4][4], bv[4][4];
        #pragma unroll
        for (int r = 0; r < 4; ++r) {
            float4 t = *reinterpret_cast<const float4*>(&s_res[(rt * 4 + r) * DD + k0]);
            av[r][0] = t.x; av[r][1] = t.y; av[r][2] = t.z; av[r][3] = t.w;
            if (!FIRST) {
                float4 u = *reinterpret_cast<const float4*>(&s_h[(rt * 4 + r) * DD + k0]);
                bv[r][0] = u.x; bv[r][1] = u.y; bv[r][2] = u.z; bv[r][3] = u.w;
            }
        }

        #pragma unroll
        for (int kk = 0; kk < 4; ++kk) {
            const float* w = wb + (size_t)(k0 + kk) * 768;
            float4 wr = *reinterpret_cast<const float4*>(w);
            float4 wi = *reinterpret_cast<const float4*>(w + 128);
            float4 wn = *reinterpret_cast<const float4*>(w + 256);
            float4 vr, vi, vn;
            if (!FIRST) {
                vr = *reinterpret_cast<const float4*>(w + 384);
                vi = *reinterpret_cast<const float4*>(w + 512);
                vn = *reinterpret_cast<const float4*>(w + 640);
            }
            #pragma unroll
            for (int r = 0; r < 4; ++r) {
                float a = av[r][kk];
                sr[r][0] += a * wr.x; sr[r][1] += a * wr.y;
                sr[r][2] += a * wr.z; sr[r][3] += a * wr.w;
                si[r][0] += a * wi.x; si[r][1] += a * wi.y;
                si[r][2] += a * wi.z; si[r][3] += a * wi.w;
                sn[r][0] += a * wn.x; sn[r][1] += a * wn.y;
                sn[r][2] += a * wn.z; sn[r][3] += a * wn.w;
                if (!FIRST) {
                    float b = bv[r][kk];
                    sr[r][0] += b * vr.x; sr[r][1] += b * vr.y;
                    sr[r][2] += b * vr.z; sr[r][3] += b * vr.w;
                    si[r][0] += b * vi.x; si[r][1] += b * vi.y;
                    si[r][2] += b * vi.z; si[r][3] += b * vi.w;
                    hn[r][0] += b * vn.x; hn[r][1] += b * vn.y;
                    hn[r][2] += b * vn.z; hn[r][3] += b * vn.w;
                }
            }
        }
    }

    float4 gv, bvln;
    if (LAST) {
        gv = *reinterpret_cast<const float4*>(lng + jb);
        bvln = *reinterpret_cast<const float4*>(lnb + jb);
    }

    #pragma unroll
    for (int r = 0; r < 4; ++r) {
        int row = row0 + rt * 4 + r;
        if (row >= NN) continue;   // uniform across the 32-lane half-wave
        float ho[4] = {0.f, 0.f, 0.f, 0.f};
        if (!FIRST) {
            float4 hold = *reinterpret_cast<const float4*>(&s_h[(rt * 4 + r) * DD + jb]);
            ho[0] = hold.x; ho[1] = hold.y; ho[2] = hold.z; ho[3] = hold.w;
        }
        float o[4];
        #pragma unroll
        for (int jj = 0; jj < 4; ++jj) {
            float rg = sigmoid_f(sr[r][jj]);
            float ig = sigmoid_f(si[r][jj]);
            float ng = tanh_f(sn[r][jj] + rg * hn[r][jj]);
            o[jj] = ng + ig * (ho[jj] - ng);
        }
        if (LAST) {
            // LayerNorm across the row's 128 outputs = 32 contiguous lanes
            float s = (o[0] + o[1]) + (o[2] + o[3]);
            #pragma unroll
            for (int m = 16; m >= 1; m >>= 1) s += __shfl_xor(s, m, 32);
            float mean = s * (1.0f / DD);
            float d[4];
            float q = 0.f;
            #pragma unroll
            for (int jj = 0; jj < 4; ++jj) { d[jj] = o[jj] - mean; q += d[jj] * d[jj]; }
            #pragma unroll
            for (int m = 16; m >= 1; m >>= 1) q += __shfl_xor(q, m, 32);
            float inv = 1.0f / sqrtf(q * (1.0f / DD) + 1e-5f);
            o[0] = d[0] * inv * gv.x + bvln.x;
            o[1] = d[1] * inv * gv.y + bvln.y;
            o[2] = d[2] * inv * gv.z + bvln.z;
            o[3] = d[3] * inv * gv.w + bvln.w;
        }
        *reinterpret_cast<float4*>(h + (size_t)row * DD + jb) =
            make_float4(o[0], o[1], o[2], o[3]);
    }
}

extern "C" void kernel_launch(void* const* d_in, const int* in_sizes, int n_in,
                              void* d_out, int out_size, void* d_ws, size_t ws_size,
                              hipStream_t stream) {
    const float* x    = (const float*)d_in[0];
    const float* vals = (const float*)d_in[1];
    const float* wx   = (const float*)d_in[2];
    const float* bx   = (const float*)d_in[3];
    const float* wh   = (const float*)d_in[4];
    const float* bh   = (const float*)d_in[5];
    const float* lng  = (const float*)d_in[6];
    const float* lnb  = (const float*)d_in[7];
    const int* rows   = (const int*)d_in[8];
    const int* cols   = (const int*)d_in[9];

    char* ws = (char*)d_ws;
    float* h   = (float*)d_out;
    float* res = (float*)ws;                       ws += (size_t)NN * DD * 4;   // 25.6 MB
    float* wpk = (float*)ws;                       ws += 128 * 6 * 128 * 4;     // 384 KB
    int* row_ptr = (int*)ws;                       ws += ((NN + 1 + 63) / 64) * 64 * 4;
    int* cnt     = (int*)ws;                       ws += ((NN + 63) / 64) * 64 * 4;
    int* cursor  = (int*)ws;                       ws += ((NN + 63) / 64) * 64 * 4;
    int* ecol    = (int*)ws;                       ws += (size_t)EE * 4;
    float* eval  = (float*)ws;                     ws += (size_t)EE * 4;

    (void)in_sizes; (void)n_in; (void)out_size; (void)ws_size;

    pack_w_kernel<<<384, 256, 0, stream>>>(wx, wh, wpk);

    const int egrid = (EE + 255) / 256;           // 2344
    const int ggrid = (NN + 3) / 4;               // 12500
    const int gru_grid = (NN + 31) / 32;          // 1563

    for (int s = 0; s < 4; ++s) {
        int k = 3 - s;  // adj_list reversed
        const int* kr = rows + (size_t)k * EE;
        const int* kc = cols + (size_t)k * EE;
        const float* kv = vals + (size_t)k * EE;

        hipMemsetAsync(cnt, 0, NN * sizeof(int), stream);
        hist_kernel<<<egrid, 256, 0, stream>>>(kr, cnt);
        scan_kernel<<<1, 1024, 0, stream>>>(cnt, row_ptr);
        hipMemcpyAsync(cursor, row_ptr, NN * sizeof(int), hipMemcpyDeviceToDevice, stream);
        scatter_kernel<<<egrid, 256, 0, stream>>>(kr, kc, kv, cursor, ecol, eval);
        gather_kernel<<<ggrid, 256, 0, stream>>>(x, row_ptr, ecol, eval, res);

        if (s == 0)
            gru_step_kernel<true, false><<<gru_grid, 256, 0, stream>>>(res, h, wpk, bx, bh, lng, lnb);
        else if (s < 3)
            gru_step_kernel<false, false><<<gru_grid, 256, 0, stream>>>(res, h, wpk, bx, bh, lng, lnb);
        else
            gru_step_kernel<false, true><<<gru_grid, 256, 0, stream>>>(res, h, wpk, bx, bh, lng, lnb);
    }
}

// Round 4
// 1198.868 us; speedup vs baseline: 1.7588x; 1.7588x over previous
//
#include <hip/hip_runtime.h>
#include <cstdint>

#define NN 50000
#define DD 128
#define EE 600000

__device__ __forceinline__ float sigmoid_f(float x) {
    return 1.0f / (1.0f + __expf(-x));
}
__device__ __forceinline__ float tanh_f(float x) {
    float e = __expf(-2.0f * fabsf(x));
    float t = (1.0f - e) / (1.0f + e);
    return copysignf(t, x);
}

// ---- weight packing: wpk[k][jg(16)][gate(6)][jj(8)] ----------------------
// Per (k, wave=jg): 48 contiguous floats, identical across lanes -> s_load.
__global__ __launch_bounds__(256) void pack_w_kernel(const float* __restrict__ wx,
                                                     const float* __restrict__ wh,
                                                     float* __restrict__ wpk) {
    int idx = blockIdx.x * 256 + threadIdx.x;
    if (idx >= 128 * 768) return;
    int k = idx / 768;
    int rem = idx - k * 768;
    int jg = rem / 48;
    int g = (rem % 48) >> 3;
    int jj = rem & 7;
    int c = jg * 8 + jj;
    float v = (g < 3) ? wx[(g * 128 + c) * 128 + k]
                      : wh[((g - 3) * 128 + c) * 128 + k];
    wpk[idx] = v;
}

// ---- CSR build (all 4 adjacencies batched) -------------------------------

__global__ __launch_bounds__(256) void hist_kernel(const int* __restrict__ rows,
                                                   int* __restrict__ cnt4) {
    int e = blockIdx.x * 256 + threadIdx.x;
    if (e >= EE) return;
    int k = blockIdx.y;
    atomicAdd(&cnt4[k * NN + rows[(size_t)k * EE + e]], 1);
}

// one block per adjacency; writes row_ptr AND cursor
__global__ __launch_bounds__(1024) void scan_kernel(const int* __restrict__ cnt4,
                                                    int* __restrict__ row_ptr4,
                                                    int* __restrict__ cursor4) {
    __shared__ int buf[1024];
    const int kadj = blockIdx.x;
    const int* cnt = cnt4 + kadj * NN;
    int* row_ptr = row_ptr4 + kadj * (NN + 1);
    int* cursor = cursor4 + kadj * NN;
    const int tid = threadIdx.x;
    const int CH = (NN + 1023) / 1024;  // 49
    const int base = tid * CH;
    int s = 0;
    #pragma unroll
    for (int i = 0; i < CH; ++i) {
        int idx = base + i;
        if (idx < NN) s += cnt[idx];
    }
    buf[tid] = s;
    __syncthreads();
    for (int d = 1; d < 1024; d <<= 1) {
        int t = (tid >= d) ? buf[tid - d] : 0;
        __syncthreads();
        buf[tid] += t;
        __syncthreads();
    }
    int run = buf[tid] - s;
    #pragma unroll
    for (int i = 0; i < CH; ++i) {
        int idx = base + i;
        if (idx < NN) {
            row_ptr[idx] = run;
            cursor[idx] = run;
            run += cnt[idx];
        }
    }
    if (tid == 0) row_ptr[NN] = EE;
}

__global__ __launch_bounds__(256) void scatter_kernel(const int* __restrict__ rows,
                                                      const int* __restrict__ cols,
                                                      const float* __restrict__ vals,
                                                      int* __restrict__ cursor4,
                                                      int2* __restrict__ epair4) {
    int e = blockIdx.x * 256 + threadIdx.x;
    if (e >= EE) return;
    int k = blockIdx.y;
    size_t off = (size_t)k * EE + e;
    int r = rows[off];
    int pos = atomicAdd(&cursor4[k * NN + r], 1);
    int2 p;
    p.x = cols[off];
    p.y = __float_as_int(vals[off]);
    epair4[(size_t)k * EE + pos] = p;
}

// ---- SpMM gather: res[r] = relu(sum val*x[col]) --------------------------
// half-wave (32 lanes) per row, float4/lane, 4-edge ILP
__global__ __launch_bounds__(256) void gather_kernel(const float* __restrict__ x,
                                                     const int* __restrict__ row_ptr,
                                                     const int2* __restrict__ epair,
                                                     float* __restrict__ res) {
    const int tid = threadIdx.x;
    const int row = blockIdx.x * 8 + (tid >> 5);
    const int d0 = (tid & 31) * 4;
    const int start = row_ptr[row];
    const int end = row_ptr[row + 1];
    float4 a0 = make_float4(0.f, 0.f, 0.f, 0.f);
    float4 a1 = a0, a2 = a0, a3 = a0;
    int e = start;
    for (; e + 3 < end; e += 4) {
        int2 p0 = epair[e], p1 = epair[e + 1], p2 = epair[e + 2], p3 = epair[e + 3];
        float4 x0 = *reinterpret_cast<const float4*>(x + (size_t)p0.x * DD + d0);
        float4 x1 = *reinterpret_cast<const float4*>(x + (size_t)p1.x * DD + d0);
        float4 x2 = *reinterpret_cast<const float4*>(x + (size_t)p2.x * DD + d0);
        float4 x3 = *reinterpret_cast<const float4*>(x + (size_t)p3.x * DD + d0);
        float v0 = __int_as_float(p0.y), v1 = __int_as_float(p1.y);
        float v2 = __int_as_float(p2.y), v3 = __int_as_float(p3.y);
        a0.x += v0 * x0.x; a0.y += v0 * x0.y; a0.z += v0 * x0.z; a0.w += v0 * x0.w;
        a1.x += v1 * x1.x; a1.y += v1 * x1.y; a1.z += v1 * x1.z; a1.w += v1 * x1.w;
        a2.x += v2 * x2.x; a2.y += v2 * x2.y; a2.z += v2 * x2.z; a2.w += v2 * x2.w;
        a3.x += v3 * x3.x; a3.y += v3 * x3.y; a3.z += v3 * x3.z; a3.w += v3 * x3.w;
    }
    for (; e < end; ++e) {
        int2 p0 = epair[e];
        float v0 = __int_as_float(p0.y);
        float4 x0 = *reinterpret_cast<const float4*>(x + (size_t)p0.x * DD + d0);
        a0.x += v0 * x0.x; a0.y += v0 * x0.y; a0.z += v0 * x0.z; a0.w += v0 * x0.w;
    }
    float4 o;
    o.x = fmaxf((a0.x + a1.x) + (a2.x + a3.x), 0.f);
    o.y = fmaxf((a0.y + a1.y) + (a2.y + a3.y), 0.f);
    o.z = fmaxf((a0.z + a1.z) + (a2.z + a3.z), 0.f);
    o.w = fmaxf((a0.w + a1.w) + (a2.w + a3.w), 0.f);
    *reinterpret_cast<float4*>(res + (size_t)row * DD + d0) = o;
}

// ---- Fused dual-GEMM + GRU ------------------------------------------------
// Block: 64 rows (lanes) x 128 cols (16 waves x 8 j). Inputs transposed in
// LDS (XOR-swizzled, conflict-free, no pad). Weights: wave-uniform scalar
// loads (SGPR) -> v_fmac with scalar operand. LDS pipe: 2 b32/k/wave.
template <bool FIRST>
__global__ __launch_bounds__(1024) void gru_step_kernel(const float* __restrict__ res,
                                                        float* __restrict__ h,
                                                        const float* __restrict__ wpk,
                                                        const float* __restrict__ bx,
                                                        const float* __restrict__ bh) {
    __shared__ float s_a[128 * 64];                 // relu(res) transposed, 32 KB
    __shared__ float s_b[FIRST ? 64 : 128 * 64];    // h transposed (unused if FIRST)

    const int tid = threadIdx.x;
    const int row0 = blockIdx.x * 64;

    // stage + transpose: idx -> (row=idx>>5, kq=(idx&31)*4); coalesced reads,
    // swizzled writes s[(k<<6) | (row ^ (k&31))]
    #pragma unroll
    for (int p = 0; p < 2; ++p) {
        int idx = p * 1024 + tid;
        int rl = idx >> 5;
        int kq = (idx & 31) * 4;
        int grow = row0 + rl;
        float4 rv = make_float4(0.f, 0.f, 0.f, 0.f);
        float4 hv = make_float4(0.f, 0.f, 0.f, 0.f);
        if (grow < NN) {
            rv = *reinterpret_cast<const float4*>(res + (size_t)grow * DD + kq);
            if (!FIRST) hv = *reinterpret_cast<const float4*>(h + (size_t)grow * DD + kq);
        }
        float rr[4] = {rv.x, rv.y, rv.z, rv.w};
        float hh[4] = {hv.x, hv.y, hv.z, hv.w};
        #pragma unroll
        for (int i = 0; i < 4; ++i) {
            int k = kq + i;
            int sw = (k << 6) | (rl ^ (k & 31));
            s_a[sw] = rr[i];
            if (!FIRST) s_b[sw] = hh[i];
        }
    }

    const int lane = tid & 63;
    const int wave = __builtin_amdgcn_readfirstlane(tid >> 6);  // 0..15, uniform
    const int jbase = wave * 8;
    const float* __restrict__ wrow = wpk + wave * 48;           // uniform base

    // accumulators: 8 j's per lane
    float sr[8], si[8], sn[8], hn[8];
    #pragma unroll
    for (int j = 0; j < 8; ++j) {
        sr[j] = bx[jbase + j] + bh[jbase + j];
        si[j] = bx[DD + jbase + j] + bh[DD + jbase + j];
        sn[j] = bx[2 * DD + jbase + j];
        hn[j] = bh[2 * DD + jbase + j];
    }

    __syncthreads();   // the only barrier

    #pragma unroll 2
    for (int k = 0; k < DD; ++k) {
        int sw = (k << 6) | (lane ^ (k & 31));
        float a = s_a[sw];
        float b = 0.f;
        if (!FIRST) b = s_b[sw];
        const float* __restrict__ w = wrow + (size_t)k * 768;   // 48 uniform floats
        #pragma unroll
        for (int j = 0; j < 8; ++j) {
            sr[j] += a * w[j];
            si[j] += a * w[8 + j];
            sn[j] += a * w[16 + j];
            if (!FIRST) {
                sr[j] += b * w[24 + j];
                si[j] += b * w[32 + j];
                hn[j] += b * w[40 + j];
            }
        }
    }

    int row = row0 + lane;
    if (row < NN) {
        float o[8];
        #pragma unroll
        for (int j = 0; j < 8; ++j) {
            int jc = jbase + j;
            float ho = 0.f;
            if (!FIRST) ho = s_b[(jc << 6) | (lane ^ (jc & 31))];
            float rg = sigmoid_f(sr[j]);
            float ig = sigmoid_f(si[j]);
            float ng = tanh_f(sn[j] + rg * hn[j]);
            o[j] = ng + ig * (ho - ng);
        }
        float* hp = h + (size_t)row * DD + jbase;
        *reinterpret_cast<float4*>(hp) = make_float4(o[0], o[1], o[2], o[3]);
        *reinterpret_cast<float4*>(hp + 4) = make_float4(o[4], o[5], o[6], o[7]);
    }
}

// LayerNorm over D=128, 32 lanes/row, two-pass variance (matches jnp.var)
__global__ __launch_bounds__(256) void ln_kernel(float* __restrict__ h,
                                                 const float* __restrict__ g,
                                                 const float* __restrict__ b) {
    int tid = threadIdx.x;
    int lane = tid & 31;
    int rl = tid >> 5;
    int row = blockIdx.x * 8 + rl;
    if (row >= NN) return;
    float4 v = *reinterpret_cast<const float4*>(h + (size_t)row * DD + lane * 4);
    float s = v.x + v.y + v.z + v.w;
    #pragma unroll
    for (int m = 16; m >= 1; m >>= 1) s += __shfl_xor(s, m, 64);
    float mean = s * (1.0f / DD);
    float dx = v.x - mean, dy = v.y - mean, dz = v.z - mean, dw = v.w - mean;
    float q = dx * dx + dy * dy + dz * dz + dw * dw;
    #pragma unroll
    for (int m = 16; m >= 1; m >>= 1) q += __shfl_xor(q, m, 64);
    float var = q * (1.0f / DD);
    float inv = 1.0f / sqrtf(var + 1e-5f);
    float4 gv = *reinterpret_cast<const float4*>(g + lane * 4);
    float4 bv = *reinterpret_cast<const float4*>(b + lane * 4);
    float4 o;
    o.x = dx * inv * gv.x + bv.x;
    o.y = dy * inv * gv.y + bv.y;
    o.z = dz * inv * gv.z + bv.z;
    o.w = dw * inv * gv.w + bv.w;
    *reinterpret_cast<float4*>(h + (size_t)row * DD + lane * 4) = o;
}

static inline size_t align_up(size_t v, size_t a) { return (v + a - 1) & ~(a - 1); }

extern "C" void kernel_launch(void* const* d_in, const int* in_sizes, int n_in,
                              void* d_out, int out_size, void* d_ws, size_t ws_size,
                              hipStream_t stream) {
    const float* x    = (const float*)d_in[0];
    const float* vals = (const float*)d_in[1];
    const float* wx   = (const float*)d_in[2];
    const float* bx   = (const float*)d_in[3];
    const float* wh   = (const float*)d_in[4];
    const float* bh   = (const float*)d_in[5];
    const float* lng  = (const float*)d_in[6];
    const float* lnb  = (const float*)d_in[7];
    const int* rows   = (const int*)d_in[8];
    const int* cols   = (const int*)d_in[9];

    float* h = (float*)d_out;

    size_t off = 0;
    char* wsb = (char*)d_ws;
    float* res = (float*)(wsb + off);      off = align_up(off + (size_t)NN * DD * 4, 256);
    float* wpk = (float*)(wsb + off);      off = align_up(off + (size_t)128 * 768 * 4, 256);
    int* row_ptr4 = (int*)(wsb + off);     off = align_up(off + (size_t)4 * (NN + 1) * 4, 256);
    int* cnt4 = (int*)(wsb + off);         off = align_up(off + (size_t)4 * NN * 4, 256);
    int* cursor4 = (int*)(wsb + off);      off = align_up(off + (size_t)4 * NN * 4, 256);
    int2* epair4 = (int2*)(wsb + off);     off = align_up(off + (size_t)4 * EE * 8, 256);

    (void)in_sizes; (void)n_in; (void)out_size; (void)ws_size;

    pack_w_kernel<<<384, 256, 0, stream>>>(wx, wh, wpk);

    hipMemsetAsync(cnt4, 0, (size_t)4 * NN * sizeof(int), stream);
    dim3 egrid((EE + 255) / 256, 4);
    hist_kernel<<<egrid, 256, 0, stream>>>(rows, cnt4);
    scan_kernel<<<4, 1024, 0, stream>>>(cnt4, row_ptr4, cursor4);
    scatter_kernel<<<egrid, 256, 0, stream>>>(rows, cols, vals, cursor4, epair4);

    const int ggrid = NN / 8;              // 6250
    const int gru_grid = (NN + 63) / 64;   // 782

    for (int s = 0; s < 4; ++s) {
        int k = 3 - s;  // adj_list reversed
        gather_kernel<<<ggrid, 256, 0, stream>>>(
            x, row_ptr4 + (size_t)k * (NN + 1), epair4 + (size_t)k * EE, res);
        if (s == 0)
            gru_step_kernel<true><<<gru_grid, 1024, 0, stream>>>(res, h, wpk, bx, bh);
        else
            gru_step_kernel<false><<<gru_grid, 1024, 0, stream>>>(res, h, wpk, bx, bh);
    }

    ln_kernel<<<(NN + 7) / 8, 256, 0, stream>>>(h, lng, lnb);
}